// Round 1
// baseline (278.017 us; speedup 1.0000x reference)
//
#include <hip/hip_runtime.h>
#include <cstdint>

// B=4, S=2048, D=1024.  M_qkv = B*S = 8192.
// ws layout (bytes):
//   x_bf   @ 0         : 8192*1024*2  = 16,777,216
//   w_bf   @ 16777216  : 3*1024*1024*2 = 6,291,456   (Wq,Wk,Wv)
//   Q      @ 23068672  : 16,777,216   (bf16 [8192][1024])
//   K      @ 39845888  : 16,777,216
//   Vt     @ 56623104  : 16,777,216   (bf16 [1024][8192], col = b*2048+s)
//   S/P    @ 73400320  : 33,554,432   (bf16 [4][2048][2048], softmax in place)
// total ~102 MB

typedef __bf16 bf16x8_t __attribute__((ext_vector_type(8)));
typedef float  f32x4_t  __attribute__((ext_vector_type(4)));

__device__ __forceinline__ uint16_t f2bf(float f) {
    union { float f; uint32_t u; } v; v.f = f;
    return (uint16_t)((v.u + 0x7fffu + ((v.u >> 16) & 1u)) >> 16);  // RNE
}
__device__ __forceinline__ float bf2f(uint16_t u) {
    union { uint32_t u; float f; } v; v.u = ((uint32_t)u) << 16;
    return v.f;
}

__device__ __forceinline__ void gload_lds16(const uint16_t* g, uint16_t* lds) {
    __builtin_amdgcn_global_load_lds(
        (const __attribute__((address_space(1))) void*)g,
        (__attribute__((address_space(3))) void*)lds, 16, 0, 0);
}

// C[m,n] = alpha * sum_k A[m,k]*B[n,k]  (+ bias)
// A: [M,K] row-major bf16, B: [N,K] row-major bf16 (i.e. B^T layout).
// BIAS: 0=none, 1=+bias[n] (col), 2=+bias[m] (row).
// grid = (M/128, N/128, Z); block = 256.
template <int BIAS, typename OutT>
__global__ __launch_bounds__(256, 3) void gemm_bt(
    const uint16_t* __restrict__ A, int lda, long long sAz,
    const uint16_t* __restrict__ B, int ldb, long long sBz,
    OutT* __restrict__ C, int ldc, long long sCz,
    const float* __restrict__ bias0, const float* __restrict__ bias1,
    int K, float alpha)
{
    __shared__ uint16_t ldsA[128 * 32];
    __shared__ uint16_t ldsB[128 * 32];

    const int tid  = threadIdx.x;
    const int wave = tid >> 6;
    const int lane = tid & 63;
    const int quad = lane >> 4;
    const int l15  = lane & 15;
    const int z    = blockIdx.z;

    A += (long long)z * sAz;
    B += (long long)z * sBz;
    C += (long long)z * sCz;

    const int m0 = blockIdx.x * 128;
    const int n0 = blockIdx.y * 128;

    // staging: 512 chunks of 16B per tile; chunk s -> row s>>2, k-chunk (s&3)*8.
    // wave-call c covers LDS chunks [(c*4+wave)*64, +64), lane L -> +L (HW: base + lane*16).
    const int sA0 = (0 * 4 + wave) * 64 + lane;
    const int sA1 = (1 * 4 + wave) * 64 + lane;
    const int r0 = sA0 >> 2, c0 = (sA0 & 3) * 8;
    const int r1 = sA1 >> 2, c1 = (sA1 & 3) * 8;

    const uint16_t* gA0 = A + (long long)(m0 + r0) * lda + c0;
    const uint16_t* gA1 = A + (long long)(m0 + r1) * lda + c1;
    const uint16_t* gB0 = B + (long long)(n0 + r0) * ldb + c0;
    const uint16_t* gB1 = B + (long long)(n0 + r1) * ldb + c1;

    uint16_t* lA0 = ldsA + (0 * 4 + wave) * 512;   // wave-uniform bases
    uint16_t* lA1 = ldsA + (1 * 4 + wave) * 512;
    uint16_t* lB0 = ldsB + (0 * 4 + wave) * 512;
    uint16_t* lB1 = ldsB + (1 * 4 + wave) * 512;

    const int m_off = (wave & 1) * 64;
    const int n_off = (wave >> 1) * 64;

    f32x4_t acc[4][4];
#pragma unroll
    for (int i = 0; i < 4; ++i)
#pragma unroll
        for (int j = 0; j < 4; ++j)
            acc[i][j] = f32x4_t{0.f, 0.f, 0.f, 0.f};

    for (int k0 = 0; k0 < K; k0 += 32) {
        gload_lds16(gA0, lA0);
        gload_lds16(gA1, lA1);
        gload_lds16(gB0, lB0);
        gload_lds16(gB1, lB1);
        gA0 += 32; gA1 += 32; gB0 += 32; gB1 += 32;
        __syncthreads();

        bf16x8_t af[4], bfr[4];
#pragma unroll
        for (int i = 0; i < 4; ++i)
            af[i] = *(const bf16x8_t*)(ldsA + (m_off + i * 16 + l15) * 32 + quad * 8);
#pragma unroll
        for (int j = 0; j < 4; ++j)
            bfr[j] = *(const bf16x8_t*)(ldsB + (n_off + j * 16 + l15) * 32 + quad * 8);
#pragma unroll
        for (int i = 0; i < 4; ++i)
#pragma unroll
            for (int j = 0; j < 4; ++j)
                acc[i][j] = __builtin_amdgcn_mfma_f32_16x16x32_bf16(af[i], bfr[j], acc[i][j], 0, 0, 0);
        __syncthreads();
    }

    const float* bias = (z == 0) ? bias0 : bias1;
#pragma unroll
    for (int i = 0; i < 4; ++i) {
        const int mb = m0 + m_off + i * 16 + quad * 4;   // rows mb..mb+3
        float rb[4];
        if (BIAS == 2) {
#pragma unroll
            for (int r = 0; r < 4; ++r) rb[r] = bias[mb + r];
        }
#pragma unroll
        for (int j = 0; j < 4; ++j) {
            const int n = n0 + n_off + j * 16 + l15;
            float cb = 0.f;
            if (BIAS == 1) cb = bias[n];
#pragma unroll
            for (int r = 0; r < 4; ++r) {
                float v = acc[i][j][r] * alpha;
                if (BIAS == 1) v += cb;
                if (BIAS == 2) v += rb[r];
                if (sizeof(OutT) == 2)
                    ((uint16_t*)C)[(long long)(mb + r) * ldc + n] = f2bf(v);
                else
                    ((float*)C)[(long long)(mb + r) * ldc + n] = v;
            }
        }
    }
}

__global__ void cvt_x(const float* __restrict__ src, uint16_t* __restrict__ dst) {
    const int i = blockIdx.x * 256 + threadIdx.x;     // 2,097,152 threads * 4 elems
    const float4 f = ((const float4*)src)[i];
    ushort4 o;
    o.x = f2bf(f.x); o.y = f2bf(f.y); o.z = f2bf(f.z); o.w = f2bf(f.w);
    ((ushort4*)dst)[i] = o;
}

__global__ void cvt_w(const float* __restrict__ Wq, const float* __restrict__ Wk,
                      const float* __restrict__ Wv, uint16_t* __restrict__ dst) {
    const int z = blockIdx.z;
    const float* s = (z == 0) ? Wq : (z == 1) ? Wk : Wv;
    const int i = blockIdx.x * 256 + threadIdx.x;     // 262,144 threads * 4 elems
    const float4 f = ((const float4*)s)[i];
    ushort4 o;
    o.x = f2bf(f.x); o.y = f2bf(f.y); o.z = f2bf(f.z); o.w = f2bf(f.w);
    ((ushort4*)(dst + (long long)z * 1048576))[i] = o;
}

// In-place row softmax over 2048 bf16 cols; one block per row.
__global__ __launch_bounds__(256) void softmax_rows(uint16_t* __restrict__ S) {
    uint16_t* p = S + (long long)blockIdx.x * 2048;
    const int tid  = threadIdx.x;
    const int wave = tid >> 6;
    const int lane = tid & 63;

    float v[8];
#pragma unroll
    for (int i = 0; i < 8; ++i) v[i] = bf2f(p[tid + i * 256]);

    float m = v[0];
#pragma unroll
    for (int i = 1; i < 8; ++i) m = fmaxf(m, v[i]);
#pragma unroll
    for (int off = 32; off > 0; off >>= 1) m = fmaxf(m, __shfl_xor(m, off));

    __shared__ float red[8];
    if (lane == 0) red[wave] = m;
    __syncthreads();
    m = fmaxf(fmaxf(red[0], red[1]), fmaxf(red[2], red[3]));

    float s = 0.f;
#pragma unroll
    for (int i = 0; i < 8; ++i) {
        v[i] = exp2f((v[i] - m) * 1.4426950408889634f);
        s += v[i];
    }
#pragma unroll
    for (int off = 32; off > 0; off >>= 1) s += __shfl_xor(s, off);
    if (lane == 0) red[4 + wave] = s;
    __syncthreads();
    s = red[4] + red[5] + red[6] + red[7];
    const float inv = 1.f / s;
#pragma unroll
    for (int i = 0; i < 8; ++i) p[tid + i * 256] = f2bf(v[i] * inv);
}

extern "C" void kernel_launch(void* const* d_in, const int* in_sizes, int n_in,
                              void* d_out, int out_size, void* d_ws, size_t ws_size,
                              hipStream_t stream) {
    const float* x  = (const float*)d_in[0];
    const float* Wq = (const float*)d_in[1];
    const float* bq = (const float*)d_in[2];
    const float* Wk = (const float*)d_in[3];
    const float* bk = (const float*)d_in[4];
    const float* Wv = (const float*)d_in[5];
    const float* bv = (const float*)d_in[6];
    float* out = (float*)d_out;

    char* w = (char*)d_ws;
    uint16_t* x_bf = (uint16_t*)(w);
    uint16_t* w_bf = (uint16_t*)(w + 16777216);
    uint16_t* Qb   = (uint16_t*)(w + 23068672);
    uint16_t* Kb   = (uint16_t*)(w + 39845888);
    uint16_t* Vt   = (uint16_t*)(w + 56623104);
    uint16_t* Sb   = (uint16_t*)(w + 73400320);

    // 1) fp32 -> bf16 conversions
    cvt_x<<<8192, 256, 0, stream>>>(x, x_bf);
    cvt_w<<<dim3(1024, 1, 3), 256, 0, stream>>>(Wq, Wk, Wv, w_bf);

    // 2) Q,K = x @ W^T + b   [8192,1024], z selects (Wq,bq,Q) / (Wk,bk,K)
    gemm_bt<1, uint16_t><<<dim3(64, 8, 2), 256, 0, stream>>>(
        x_bf, 1024, 0LL,
        w_bf, 1024, 1048576LL,
        Qb, 1024, 8388608LL,
        bq, bk, 1024, 1.0f);

    // 2b) Vt[e, b*2048+s] = sum_d Wv[e,d]*x[s,d] + bv[e]   [1024,8192], row bias
    gemm_bt<2, uint16_t><<<dim3(8, 64, 1), 256, 0, stream>>>(
        w_bf + 2097152, 1024, 0LL,
        x_bf, 1024, 0LL,
        Vt, 8192, 0LL,
        bv, bv, 1024, 1.0f);

    // 3) S_b = (Q_b K_b^T) / 32   [2048,2048] per batch, bf16
    gemm_bt<0, uint16_t><<<dim3(16, 16, 4), 256, 0, stream>>>(
        Qb, 1024, 2097152LL,
        Kb, 1024, 2097152LL,
        Sb, 2048, 4194304LL,
        nullptr, nullptr, 1024, 0.03125f);

    // 4) softmax rows in place (4*2048 rows)
    softmax_rows<<<8192, 256, 0, stream>>>(Sb);

    // 5) O_b = P_b @ V_b : C[q,d] = sum_k P[q,k] * Vt[d, b*2048+k]  -> fp32 d_out
    gemm_bt<0, float><<<dim3(16, 8, 4), 256, 0, stream>>>(
        Sb, 2048, 4194304LL,
        Vt, 8192, 2048LL,
        out, 1024, 2097152LL,
        nullptr, nullptr, 2048, 1.0f);
}

// Round 2
// 239.931 us; speedup vs baseline: 1.1587x; 1.1587x over previous
//
#include <hip/hip_runtime.h>
#include <cstdint>

// B=4, S=2048, D=1024.  M_qkv = B*S = 8192.
// ws layout (bytes):
//   x_bf   @ 0         : 16,777,216   bf16 [8192][1024]
//   w_bf   @ 16777216  :  6,291,456   bf16 Wq,Wk,Wv each [1024][1024]
//   Q      @ 23068672  : 16,777,216   bf16 [8192][1024]
//   K      @ 39845888  : 16,777,216
//   Vt     @ 56623104  : 16,777,216   bf16 [1024][8192], col = b*2048+s
//   S/P    @ 73400320  : 33,554,432   bf16 [4][2048][2048], softmax in place
// total ~102 MB

typedef __bf16 bf16x8_t __attribute__((ext_vector_type(8)));
typedef float  f32x4_t  __attribute__((ext_vector_type(4)));

__device__ __forceinline__ uint16_t f2bf(float f) {
    union { float f; uint32_t u; } v; v.f = f;
    return (uint16_t)((v.u + 0x7fffu + ((v.u >> 16) & 1u)) >> 16);  // RNE
}
__device__ __forceinline__ float bf2f(uint16_t u) {
    union { uint32_t u; float f; } v; v.u = ((uint32_t)u) << 16;
    return v.f;
}

__device__ __forceinline__ void gload_lds16(const uint16_t* g, uint16_t* lds) {
    __builtin_amdgcn_global_load_lds(
        (const __attribute__((address_space(1))) void*)g,
        (__attribute__((address_space(3))) void*)lds, 16, 0, 0);
}

// C[m,n] = alpha * sum_k A[m,k]*B[n,k]  (+ bias)
// A: [M,K] row-major bf16, B: [N,K] row-major bf16 (B^T layout).
// BIAS: 0=none, 1=+bias[n] (col), 2=+bias[m] (row).
// grid = (M/128, N/128, Z); block = 256.  BK=64, XOR-swizzled LDS.
//
// Swizzle: LDS slot (row r, chunk c) holds global chunk (r, c ^ (r&7)); the
// global source address per lane is free while global_load_lds forces the LDS
// dest to base+lane*16.  Fragment (m, k=t*32+quad*8) = global chunk (m,t*4+quad)
// lives at LDS m*64 + ((t*4+quad)^(m&7))*8; m&7==l15&7, so reads within a quad
// spread over 8 distinct 4-bank groups -> uniform 2-way (free per m136).
template <int BIAS, typename OutT>
__global__ __launch_bounds__(256, 3) void gemm_bt(
    const uint16_t* __restrict__ A, int lda, long long sAz,
    const uint16_t* __restrict__ B, int ldb, long long sBz,
    OutT* __restrict__ C, int ldc, long long sCz,
    const float* __restrict__ bias0, const float* __restrict__ bias1,
    int K, float alpha)
{
    __shared__ uint16_t ldsA[128 * 64];
    __shared__ uint16_t ldsB[128 * 64];

    const int tid  = threadIdx.x;
    const int wave = tid >> 6;
    const int lane = tid & 63;
    const int quad = lane >> 4;
    const int l15  = lane & 15;
    const int z    = blockIdx.z;

    A += (long long)z * sAz;
    B += (long long)z * sBz;
    C += (long long)z * sCz;

    const int m0 = blockIdx.x * 128;
    const int n0 = blockIdx.y * 128;

    // staging: 1024 16B-chunks per 128x64 tile; slot s -> row s>>3, chunk s&7,
    // global chunk col swizzled by row.
    const uint16_t* gA[4];
    const uint16_t* gB[4];
    uint16_t* lA[4];
    uint16_t* lB[4];
#pragma unroll
    for (int c = 0; c < 4; ++c) {
        const int s   = (c * 4 + wave) * 64 + lane;
        const int r   = s >> 3;
        const int col = ((s & 7) ^ (r & 7)) * 8;
        gA[c] = A + (long long)(m0 + r) * lda + col;
        gB[c] = B + (long long)(n0 + r) * ldb + col;
        lA[c] = ldsA + (c * 4 + wave) * 512;   // wave-uniform base
        lB[c] = ldsB + (c * 4 + wave) * 512;
    }

    const int m_off = (wave & 1) * 64;
    const int n_off = (wave >> 1) * 64;

    f32x4_t acc[4][4];
#pragma unroll
    for (int i = 0; i < 4; ++i)
#pragma unroll
        for (int j = 0; j < 4; ++j)
            acc[i][j] = f32x4_t{0.f, 0.f, 0.f, 0.f};

    for (int k0 = 0; k0 < K; k0 += 64) {
#pragma unroll
        for (int c = 0; c < 4; ++c) gload_lds16(gA[c], lA[c]);
#pragma unroll
        for (int c = 0; c < 4; ++c) gload_lds16(gB[c], lB[c]);
#pragma unroll
        for (int c = 0; c < 4; ++c) { gA[c] += 64; gB[c] += 64; }
        __syncthreads();

#pragma unroll
        for (int t = 0; t < 2; ++t) {
            const int csw = (((t * 4 + quad) ^ (l15 & 7))) * 8;
            bf16x8_t af[4], bfr[4];
#pragma unroll
            for (int i = 0; i < 4; ++i)
                af[i] = *(const bf16x8_t*)(ldsA + (m_off + i * 16 + l15) * 64 + csw);
#pragma unroll
            for (int j = 0; j < 4; ++j)
                bfr[j] = *(const bf16x8_t*)(ldsB + (n_off + j * 16 + l15) * 64 + csw);
#pragma unroll
            for (int i = 0; i < 4; ++i)
#pragma unroll
                for (int j = 0; j < 4; ++j)
                    acc[i][j] = __builtin_amdgcn_mfma_f32_16x16x32_bf16(af[i], bfr[j], acc[i][j], 0, 0, 0);
        }
        __syncthreads();
    }

    const float* bias = (z == 0) ? bias0 : bias1;
#pragma unroll
    for (int i = 0; i < 4; ++i) {
        const int mb = m0 + m_off + i * 16 + quad * 4;   // rows mb..mb+3
        float rb[4];
        if (BIAS == 2) {
#pragma unroll
            for (int r = 0; r < 4; ++r) rb[r] = bias[mb + r];
        }
#pragma unroll
        for (int j = 0; j < 4; ++j) {
            const int n = n0 + n_off + j * 16 + l15;
            float cb = 0.f;
            if (BIAS == 1) cb = bias[n];
#pragma unroll
            for (int r = 0; r < 4; ++r) {
                float v = acc[i][j][r] * alpha;
                if (BIAS == 1) v += cb;
                if (BIAS == 2) v += rb[r];
                if (sizeof(OutT) == 2)
                    ((uint16_t*)C)[(long long)(mb + r) * ldc + n] = f2bf(v);
                else
                    ((float*)C)[(long long)(mb + r) * ldc + n] = v;
            }
        }
    }
}

// fp32 -> bf16 for x (blocks 0..8191) and Wq/Wk/Wv (blocks 8192..11263).
__global__ void cvt_all(const float* __restrict__ x,
                        const float* __restrict__ Wq, const float* __restrict__ Wk,
                        const float* __restrict__ Wv,
                        uint16_t* __restrict__ x_bf, uint16_t* __restrict__ w_bf) {
    const int b = blockIdx.x;
    const float* src;
    uint16_t* dst;
    int i;
    if (b < 8192) {
        src = x; dst = x_bf; i = b * 256 + threadIdx.x;
    } else {
        const int wz = (b - 8192) >> 10;
        const int rb = (b - 8192) & 1023;
        src = (wz == 0) ? Wq : (wz == 1) ? Wk : Wv;
        dst = w_bf + (long long)wz * 1048576;
        i = rb * 256 + threadIdx.x;
    }
    const float4 f = ((const float4*)src)[i];
    ushort4 o;
    o.x = f2bf(f.x); o.y = f2bf(f.y); o.z = f2bf(f.z); o.w = f2bf(f.w);
    ((ushort4*)dst)[i] = o;
}

// In-place row softmax over 2048 bf16 cols; one block per row; 16B/lane loads.
__global__ __launch_bounds__(256) void softmax_rows(uint16_t* __restrict__ S) {
    uint16_t* p = S + (long long)blockIdx.x * 2048;
    const int tid  = threadIdx.x;
    const int wave = tid >> 6;
    const int lane = tid & 63;

    const ushort4 a0 = *(const ushort4*)(p + tid * 8);
    const ushort4 a1 = *(const ushort4*)(p + tid * 8 + 4);
    float v[8] = {bf2f(a0.x), bf2f(a0.y), bf2f(a0.z), bf2f(a0.w),
                  bf2f(a1.x), bf2f(a1.y), bf2f(a1.z), bf2f(a1.w)};

    float m = v[0];
#pragma unroll
    for (int i = 1; i < 8; ++i) m = fmaxf(m, v[i]);
#pragma unroll
    for (int off = 32; off > 0; off >>= 1) m = fmaxf(m, __shfl_xor(m, off));

    __shared__ float red[8];
    if (lane == 0) red[wave] = m;
    __syncthreads();
    m = fmaxf(fmaxf(red[0], red[1]), fmaxf(red[2], red[3]));

    float s = 0.f;
#pragma unroll
    for (int i = 0; i < 8; ++i) {
        v[i] = exp2f((v[i] - m) * 1.4426950408889634f);
        s += v[i];
    }
#pragma unroll
    for (int off = 32; off > 0; off >>= 1) s += __shfl_xor(s, off);
    if (lane == 0) red[4 + wave] = s;
    __syncthreads();
    s = red[4] + red[5] + red[6] + red[7];
    const float inv = 1.f / s;

    ushort4 o0, o1;
    o0.x = f2bf(v[0] * inv); o0.y = f2bf(v[1] * inv);
    o0.z = f2bf(v[2] * inv); o0.w = f2bf(v[3] * inv);
    o1.x = f2bf(v[4] * inv); o1.y = f2bf(v[5] * inv);
    o1.z = f2bf(v[6] * inv); o1.w = f2bf(v[7] * inv);
    *(ushort4*)(p + tid * 8)     = o0;
    *(ushort4*)(p + tid * 8 + 4) = o1;
}

extern "C" void kernel_launch(void* const* d_in, const int* in_sizes, int n_in,
                              void* d_out, int out_size, void* d_ws, size_t ws_size,
                              hipStream_t stream) {
    const float* x  = (const float*)d_in[0];
    const float* Wq = (const float*)d_in[1];
    const float* bq = (const float*)d_in[2];
    const float* Wk = (const float*)d_in[3];
    const float* bk = (const float*)d_in[4];
    const float* Wv = (const float*)d_in[5];
    const float* bv = (const float*)d_in[6];
    float* out = (float*)d_out;

    char* w = (char*)d_ws;
    uint16_t* x_bf = (uint16_t*)(w);
    uint16_t* w_bf = (uint16_t*)(w + 16777216);
    uint16_t* Qb   = (uint16_t*)(w + 23068672);
    uint16_t* Kb   = (uint16_t*)(w + 39845888);
    uint16_t* Vt   = (uint16_t*)(w + 56623104);
    uint16_t* Sb   = (uint16_t*)(w + 73400320);

    // 1) fp32 -> bf16 conversions (x + all three W)
    cvt_all<<<11264, 256, 0, stream>>>(x, Wq, Wk, Wv, x_bf, w_bf);

    // 2) Q,K = x @ W^T + b   [8192,1024]; z selects (Wq,bq,Q)/(Wk,bk,K)
    gemm_bt<1, uint16_t><<<dim3(64, 8, 2), 256, 0, stream>>>(
        x_bf, 1024, 0LL,
        w_bf, 1024, 1048576LL,
        Qb, 1024, 8388608LL,
        bq, bk, 1024, 1.0f);

    // 2b) Vt[e, b*2048+s] = sum_d Wv[e,d]*x[s,d] + bv[e]   [1024,8192], row bias
    gemm_bt<2, uint16_t><<<dim3(8, 64, 1), 256, 0, stream>>>(
        w_bf + 2097152, 1024, 0LL,
        x_bf, 1024, 0LL,
        Vt, 8192, 0LL,
        bv, bv, 1024, 1.0f);

    // 3) S_b = (Q_b K_b^T) / 32   [2048,2048] per batch, bf16
    gemm_bt<0, uint16_t><<<dim3(16, 16, 4), 256, 0, stream>>>(
        Qb, 1024, 2097152LL,
        Kb, 1024, 2097152LL,
        Sb, 2048, 4194304LL,
        nullptr, nullptr, 1024, 0.03125f);

    // 4) softmax rows in place (4*2048 rows)
    softmax_rows<<<8192, 256, 0, stream>>>(Sb);

    // 5) O_b = P_b @ V_b : C[q,d] = sum_k P[q,k] * Vt[d, b*2048+k] -> fp32 out
    gemm_bt<0, float><<<dim3(16, 8, 4), 256, 0, stream>>>(
        Sb, 2048, 4194304LL,
        Vt, 8192, 2048LL,
        out, 1024, 2097152LL,
        nullptr, nullptr, 2048, 1.0f);
}